// Round 12
// baseline (104.502 us; speedup 1.0000x reference)
//
#include <hip/hip_runtime.h>
#include <math.h>

#define B_ 2
#define C_ 128
#define H_ 64
#define W_ 64
#define F_ 16
#define U_ 9
#define MD_ 4
#define HW_ (H_*W_)
#define BF_ (B_*F_)

typedef float f32x4 __attribute__((ext_vector_type(4)));
typedef float f32x2 __attribute__((ext_vector_type(2)));
typedef _Float16 f16x2 __attribute__((ext_vector_type(2)));
typedef _Float16 f16x4 __attribute__((ext_vector_type(4)));
typedef _Float16 f16x8 __attribute__((ext_vector_type(8)));

// Scales (exact powers of two; leaky_relu commutes with positive scaling).
// fp16 hi/lo split -> ~2^-21 rel error per term (verified r2/r4..r11).
#define XSCALE   64.0f
#define WSCALE   256.0f
#define UNSCALE  (1.0f / 16384.0f)

// LDS map (floats), per 768-thr block (16-px tile):
//  main loop: [0,7344) tar buf0 [seg*34+c] ; [7344,14688) tar buf1 ;
//             [14688,16800) refT[px*132+c]
//  epilogue (dead staging regions after last kc barrier):
//   [0,3168)      MX[(ch*4+grp)*66 + ml*4]   per-chunk cell max (12 chunks)
//   [3168,6336)   IX[...]                    per-chunk cell argmax (as float)
//   [6336,12672)  SB[(q2*12+ch)*4+grp][ml*4] 2 partial sums per round
//   [12672,12688) fx ; [12688,12704) fy
#define TB0  0
#define TB1  7344
#define TSTR 34
#define REFO 14688
#define MXo  0
#define IXo  3168
#define SBo  6336
#define FX_  12672
#define FY_  12688
#define LDSZ 16800

static __device__ __forceinline__ f16x8 cat4(f16x2 a, f16x2 b, f16x2 c, f16x2 d) {
    f16x4 ab = __builtin_shufflevector(a, b, 0, 1, 2, 3);
    f16x4 cd = __builtin_shufflevector(c, d, 0, 1, 2, 3);
    return __builtin_shufflevector(ab, cd, 0, 1, 2, 3, 4, 5, 6, 7);
}

// exact hi/lo fp16 split of a packed f32 pair
static __device__ __forceinline__ void split2(f32x2 p, f16x2& hi, f16x2& lo) {
    hi = __builtin_bit_cast(f16x2, __builtin_amdgcn_cvt_pkrtz(p.x, p.y));
    f32x2 hf; hf.x = (float)hi.x; hf.y = (float)hi.y;
    f32x2 l = p - hf;
    lo = __builtin_bit_cast(f16x2, __builtin_amdgcn_cvt_pkrtz(l.x, l.y));
}

// Fused cost-volume + flow_reg + warp v8: 12-wave blocks for 24 waves/CU.
// Theory: r7-r11 pinned at 16 waves/CU (grid 512 x 8-wave blocks, VGPR<=128),
// VALUBusy ~35% -> latency-bound. 12-wave blocks shrink acc to 7 uv/wave
// (28 VGPR) and drop the staging prefetch regs (TLP replaces ILP), fitting
// the 80-VGPR budget of 6 waves/SIMD. launch_bounds(768,2) = min 2 blocks/CU
// (empirical: 2nd arg acts as min-blocks/CU on this toolchain).
// MFMA 16x16x32_f16: A = W[16f][32c], B = X[32c][16px]; D row f=grp*4+r, col=ml
// (fragment mapping verified r2..r11).
__global__ __launch_bounds__(768, 2)
void fused_kernel(const float* __restrict__ ref,
                  const float* __restrict__ tar,
                  const float* __restrict__ pw,
                  float* __restrict__ out0,
                  float* __restrict__ warped) {
    const int t    = threadIdx.x;
    const int lane = t & 63;
    const int wid  = t >> 6;            // wave = uv-chunk, 0..11
    const int ml   = lane & 15;         // B col = pixel ; A row = f
    const int grp  = lane >> 4;         // k-group (c = grp*8+j) ; D: f = grp*4+r

    // XCD-chunked bijective decode: grid 512 = 8 XCD x 64 contiguous (b,y,xq)
    const int n0 = blockIdx.x;
    const int L  = (n0 & 7) * 64 + (n0 >> 3);
    const int b  = L >> 8;
    const int y  = (L >> 2) & 63;
    const int x0 = (L & 3) * 16;

    // chunk partition: waves 0-8 -> 7 uv, waves 9-11 -> 6 uv (ascending)
    const bool big = (wid < 9);
    const int start = __builtin_amdgcn_readfirstlane(
        big ? wid * 7 : 63 + (wid - 9) * 6);

    __shared__ float lds[LDSZ];

    const float* refB = ref + ((size_t)b * C_) * HW_ + y * W_ + x0;
    const float* tarB = tar + ((size_t)b * C_) * HW_;

    // per-uv decode (start is SGPR -> these stay scalar)
    int off[7], uA[7], vA[7];
    #pragma unroll
    for (int i = 0; i < 7; ++i) {
        int uv = start + i;
        int uu = uv / 9;
        uA[i] = uu; vA[i] = uv - uu * 9;
        off[i] = (vA[i] * 24 + uu) * TSTR;
    }
    const int mlg = ml * TSTR + grp * 8;

    // ---- staging role: t<432 -> seg = t>>1 (r=seg/24,col=seg%24), 16 c each
    const int seg   = t >> 1;
    const int chalf = (t & 1) * 16;
    const bool sact = (seg < 216);
    const int sr   = seg / 24;
    const int scol = seg - sr * 24;
    const int ysr  = y + sr - 4;
    const int xg   = x0 - 4 + scol;
    const bool sok = sact && ((unsigned)ysr < 64u) && ((unsigned)xg < 64u);
    const int ysc  = ysr < 0 ? 0 : (ysr > 63 ? 63 : ysr);
    const int xgc  = xg  < 0 ? 0 : (xg  > 63 ? 63 : xg);
    const float* tS = tarB + (size_t)chalf * HW_ + ysc * W_ + xgc;

    // load+write fused (no prefetch regs: 24 waves/CU of TLP cover the stall)
    auto STAGE = [&](int kcv, int bufbase, bool zfill) {
        if (sok) {
            float* dst = lds + bufbase + seg * TSTR + chalf;
            const float* g = tS + (size_t)(kcv * 32) * HW_;
            #pragma unroll
            for (int c0 = 0; c0 < 16; ++c0) dst[c0] = g[(size_t)c0 * HW_];
        } else if (sact && zfill) {
            float* dst = lds + bufbase + seg * TSTR + chalf;
            #pragma unroll
            for (int c0 = 0; c0 < 16; ++c0) dst[c0] = 0.f;
        }
    };

    f32x4 acc[7];
    #pragma unroll
    for (int i = 0; i < 7; ++i) acc[i] = f32x4{0.f, 0.f, 0.f, 0.f};

    // ---- prologue: stage ref (x64) + kc0 into buf0 ----
    #pragma unroll
    for (int it = 0; it < 3; ++it) {
        int idx = it * 768 + t;
        if (idx < 2048) {
            int c = idx >> 4, px = idx & 15;
            lds[REFO + px * 132 + c] = refB[(size_t)c * HW_ + px] * XSCALE;
        }
    }
    STAGE(0, TB0, true);
    __syncthreads();

    #pragma unroll
    for (int kc = 0; kc < 4; ++kc) {
        const int tb = (kc & 1) ? TB1 : TB0;
        // stage kc+1 into the other buffer (its readers finished at the
        // end-of-(kc-1) barrier); zero-fill only on first use of each buffer
        if (kc == 0) STAGE(1, TB1, true);
        else if (kc == 1) STAGE(2, TB0, false);
        else if (kc == 2) STAGE(3, TB1, false);

        f32x4 wa = *(const f32x4*)(pw + ml * C_ + kc * 32 + grp * 8);
        f32x4 wb = *(const f32x4*)(pw + ml * C_ + kc * 32 + grp * 8 + 4);
        f16x2 wh[4], wl[4];
        {
            f32x2 p;
            p.x = wa.x * WSCALE; p.y = wa.y * WSCALE; split2(p, wh[0], wl[0]);
            p.x = wa.z * WSCALE; p.y = wa.w * WSCALE; split2(p, wh[1], wl[1]);
            p.x = wb.x * WSCALE; p.y = wb.y * WSCALE; split2(p, wh[2], wl[2]);
            p.x = wb.z * WSCALE; p.y = wb.w * WSCALE; split2(p, wh[3], wl[3]);
        }
        f16x8 whi = cat4(wh[0], wh[1], wh[2], wh[3]);
        f16x8 wlo = cat4(wl[0], wl[1], wl[2], wl[3]);

        // ref fragment: 2 x ds_read_b128, stride 132
        f32x4 rva = *(const f32x4*)(lds + REFO + ml * 132 + kc * 32 + grp * 8);
        f32x4 rvb = *(const f32x4*)(lds + REFO + ml * 132 + kc * 32 + grp * 8 + 4);
        f32x2 rv2[4];
        rv2[0].x = rva.x; rv2[0].y = rva.y;
        rv2[1].x = rva.z; rv2[1].y = rva.w;
        rv2[2].x = rvb.x; rv2[2].y = rvb.y;
        rv2[3].x = rvb.z; rv2[3].y = rvb.w;

#define UVBODY(i) {                                                           \
        const float* tp = lds + tb + off[i] + mlg;                            \
        f16x2 xh4[4], xl4[4];                                                 \
        _Pragma("unroll")                                                     \
        for (int jp = 0; jp < 4; ++jp) {                                      \
            f32x2 tj = *(const f32x2*)(tp + 2 * jp);                          \
            f32x2 p  = rv2[jp] * tj;                                          \
            f32x2 p1 = p * 0.1f;                                              \
            p = __builtin_elementwise_max(p, p1);                             \
            split2(p, xh4[jp], xl4[jp]);                                      \
        }                                                                     \
        f16x8 xhi = cat4(xh4[0], xh4[1], xh4[2], xh4[3]);                     \
        f16x8 xlo = cat4(xl4[0], xl4[1], xl4[2], xl4[3]);                     \
        acc[i] = __builtin_amdgcn_mfma_f32_16x16x32_f16(whi, xhi, acc[i], 0, 0, 0); \
        acc[i] = __builtin_amdgcn_mfma_f32_16x16x32_f16(wlo, xhi, acc[i], 0, 0, 0); \
        acc[i] = __builtin_amdgcn_mfma_f32_16x16x32_f16(whi, xlo, acc[i], 0, 0, 0); }

        #pragma unroll
        for (int i = 0; i < 6; ++i) UVBODY(i);
        if (big) UVBODY(6);

        __syncthreads();                 // single barrier per kc (dbuf)
    }

    // ================= register-resident flow_reg epilogue =================
    #pragma unroll
    for (int i = 0; i < 7; ++i) acc[i] = acc[i] * UNSCALE;   // exact pow2

    // ---- Phase A: per-chunk cell max/argmax in registers (ascending, >) ----
    f32x4 mx = acc[0];
    f32x4 bix = f32x4{(float)start, (float)start, (float)start, (float)start};
    #pragma unroll
    for (int i = 1; i < 6; ++i)
        #pragma unroll
        for (int r = 0; r < 4; ++r)
            if (acc[i][r] > mx[r]) { mx[r] = acc[i][r]; bix[r] = (float)(start + i); }
    if (big) {
        #pragma unroll
        for (int r = 0; r < 4; ++r)
            if (acc[6][r] > mx[r]) { mx[r] = acc[6][r]; bix[r] = (float)(start + 6); }
    }
    *(f32x4*)(lds + MXo + (wid * 4 + grp) * 66 + ml * 4) = mx;
    *(f32x4*)(lds + IXo + (wid * 4 + grp) * 66 + ml * 4) = bix;
    __syncthreads();

    // ---- Phase B: global max/argmax per cell (12 chunks ascending) ----
    f32x4 gm = *(const f32x4*)(lds + MXo + grp * 66 + ml * 4);
    f32x4 gb = *(const f32x4*)(lds + IXo + grp * 66 + ml * 4);
    #pragma unroll
    for (int ch = 1; ch < 12; ++ch) {
        f32x4 cm = *(const f32x4*)(lds + MXo + (ch * 4 + grp) * 66 + ml * 4);
        f32x4 cb = *(const f32x4*)(lds + IXo + (ch * 4 + grp) * 66 + ml * 4);
        #pragma unroll
        for (int r = 0; r < 4; ++r)
            if (cm[r] > gm[r]) { gm[r] = cm[r]; gb[r] = cb[r]; }
    }
    int ub[4], vb[4];
    #pragma unroll
    for (int r = 0; r < 4; ++r) {
        int bI = (int)gb[r];
        ub[r] = bI / 9; vb[r] = bI - 9 * ub[r];
    }

    float S[4]  = {0.f,0.f,0.f,0.f}, Aa[4] = {0.f,0.f,0.f,0.f};
    float Sx[4] = {0.f,0.f,0.f,0.f}, Sy[4] = {0.f,0.f,0.f,0.f};
    float gS[4] = {0.f,0.f,0.f,0.f}, gA[4] = {0.f,0.f,0.f,0.f};
#define PHB(i) {                                                              \
        _Pragma("unroll")                                                     \
        for (int r = 0; r < 4; ++r) {                                         \
            float d = acc[i][r] - gm[r];                                      \
            float z = __expf(d);                                              \
            gS[r] += z; gA[r] = fmaf(z, d, gA[r]);                            \
            int duc = uA[i] - ub[r], dvc = vA[i] - vb[r];                     \
            bool msk = (duc <= 3) && (duc >= -3) && (dvc <= 3) && (dvc >= -3);\
            float zm = msk ? z : 0.f, dm = msk ? d : 0.f;                     \
            S[r] += zm; Aa[r] = fmaf(zm, dm, Aa[r]);                          \
            Sx[r] = fmaf(zm, (float)(uA[i] - MD_), Sx[r]);                    \
            Sy[r] = fmaf(zm, (float)(vA[i] - MD_), Sy[r]);                    \
        } }
    #pragma unroll
    for (int i = 0; i < 6; ++i) PHB(i);
    if (big) PHB(6);

    // ---- Phase C: 3 rounds of 2 partial sums (fits dead staging LDS) ----
    float rq[6];
    const int cml = t & 15, cgrp = (t >> 4) & 3;   // t<64 reduction cell
#define ROUND(QA, QB, RA, RB) {                                               \
        *(f32x4*)(lds + SBo + ((0 * 12 + wid) * 4 + grp) * 66 + ml * 4) =     \
            f32x4{QA[0], QA[1], QA[2], QA[3]};                                \
        *(f32x4*)(lds + SBo + ((1 * 12 + wid) * 4 + grp) * 66 + ml * 4) =     \
            f32x4{QB[0], QB[1], QB[2], QB[3]};                                \
        __syncthreads();                                                      \
        if (t < 64) {                                                         \
            f32x4 sa = *(const f32x4*)(lds + SBo + ((0) * 4 + cgrp) * 66 + cml * 4); \
            f32x4 sb = *(const f32x4*)(lds + SBo + ((12) * 4 + cgrp) * 66 + cml * 4); \
            _Pragma("unroll")                                                 \
            for (int ch = 1; ch < 12; ++ch) {                                 \
                sa += *(const f32x4*)(lds + SBo + ((ch) * 4 + cgrp) * 66 + cml * 4);      \
                sb += *(const f32x4*)(lds + SBo + ((12 + ch) * 4 + cgrp) * 66 + cml * 4); \
            }                                                                 \
            RA = sa; RB = sb;                                                 \
        }                                                                     \
        __syncthreads(); }
    f32x4 r0v, r1v, r2v, r3v, r4v, r5v;
    ROUND(S,  Aa, r0v, r1v)
    ROUND(Sx, Sy, r2v, r3v)
    ROUND(gS, gA, r4v, r5v)

    if (t < 64) {
        #pragma unroll
        for (int r = 0; r < 4; ++r) {
            float invS = 1.f / r0v[r];
            float outx = r2v[r] * invS;
            float outy = r3v[r] * invS;
            float lent = (logf(r0v[r]) - r1v[r] * invS) * (1.0f / logf(49.0f));
            float gent = (logf(r4v[r]) - r5v[r] / r4v[r]) * (1.0f / logf(81.0f));
            float* op = out0 + ((size_t)(b * F_ + cgrp * 4 + r) * 4) * HW_
                      + y * W_ + x0 + cml;
            op[0 * HW_] = outx;
            op[1 * HW_] = outy;
            op[2 * HW_] = lent;
            op[3 * HW_] = gent;
            if (r == 0 && cgrp == 0) { lds[FX_ + cml] = outx; lds[FY_ + cml] = outy; }
        }
    }
    __syncthreads();

    // ---- fused warp tail: threads t<512, 16 px x 128 c (flow = f0) ----
    if (t < 512) {
        const int pxi = t & 15;
        const int xw  = x0 + pxi;
        float fx = lds[FX_ + pxi], fy = lds[FY_ + pxi];
        float pxw = (float)xw + fx;
        float pyw = (float)y  + fy;
        bool inb = (fabsf(2.0f * pxw / 63.0f - 1.0f) < 1.0f) &&
                   (fabsf(2.0f * pyw / 63.0f - 1.0f) < 1.0f);
        float xf = floorf(pxw), yf = floorf(pyw);
        float wx = pxw - xf, wy = pyw - yf;
        int x0i = (int)xf, y0i = (int)yf;
        auto offn = [&](int yi, int xi, float wgt, float& mw) -> int {
            bool v = ((unsigned)xi < (unsigned)W_) && ((unsigned)yi < (unsigned)H_);
            int xc = xi < 0 ? 0 : (xi > W_ - 1 ? W_ - 1 : xi);
            int yc = yi < 0 ? 0 : (yi > H_ - 1 ? H_ - 1 : yi);
            mw = v ? wgt : 0.f;
            return yc * W_ + xc;
        };
        float m00, m01, m10, m11;
        int o00 = offn(y0i,     x0i,     (1.f - wx) * (1.f - wy), m00);
        int o01 = offn(y0i,     x0i + 1, wx * (1.f - wy),         m01);
        int o10 = offn(y0i + 1, x0i,     (1.f - wx) * wy,         m10);
        int o11 = offn(y0i + 1, x0i + 1, wx * wy,                 m11);
        #pragma unroll
        for (int it = 0; it < 4; ++it) {
            int c = (t >> 4) + 32 * it;
            const float* img = tarB + (size_t)c * HW_;
            float a = img[o00] * m00 + img[o01] * m01
                    + img[o10] * m10 + img[o11] * m11;
            warped[((size_t)(b * C_ + c)) * HW_ + y * W_ + xw] = inb ? a : 0.f;
        }
    }
}

extern "C" void kernel_launch(void* const* d_in, const int* in_sizes, int n_in,
                              void* d_out, int out_size, void* d_ws, size_t ws_size,
                              hipStream_t stream) {
    const float* ref = (const float*)d_in[0];
    const float* tar = (const float*)d_in[1];
    const float* pw  = (const float*)d_in[2];
    float* out0 = (float*)d_out;                       // (B*F, 4, H, W)
    float* out1 = out0 + (size_t)BF_ * 4 * HW_;        // (B, C, H, W)
    (void)d_ws; (void)ws_size;                         // workspace unused

    fused_kernel<<<512, 768, 0, stream>>>(ref, tar, pw, out0, out1);
}

// Round 13
// 96.869 us; speedup vs baseline: 1.0788x; 1.0788x over previous
//
#include <hip/hip_runtime.h>
#include <math.h>

#define B_ 2
#define C_ 128
#define H_ 64
#define W_ 64
#define F_ 16
#define U_ 9
#define MD_ 4
#define HW_ (H_*W_)
#define BF_ (B_*F_)

typedef float f32x4 __attribute__((ext_vector_type(4)));
typedef float f32x2 __attribute__((ext_vector_type(2)));
typedef _Float16 f16x2 __attribute__((ext_vector_type(2)));
typedef _Float16 f16x4 __attribute__((ext_vector_type(4)));
typedef _Float16 f16x8 __attribute__((ext_vector_type(8)));

// Scales (exact powers of two; leaky_relu commutes with positive scaling).
// fp16 hi/lo split -> ~2^-21 rel error per term (verified r2/r4..r12).
#define XSCALE   64.0f
#define WSCALE   256.0f
#define UNSCALE  (1.0f / 16384.0f)

// LDS map (floats), per 512-thr block (16-px tile):
//  main loop: [0,7128)   tar buf [seg*33 + c], seg=r*24+col (r 0..8, col 0..23)
//             [7128,9240) refT[px*132 + c], px 0..15, c 0..127 (staged once)
//  TSTR=33: 33 = 1 (mod 32) -> staging writes AND uv reads hit each bank
//  exactly 2x (free). TSTR=34 was 2 (mod 32) -> 4-way conflicts (r12: 2.1M).
//  epilogue overlays (regions dead after their producers):
//   [0,2112)  MX[(ch*4+grp)*66+ml*4] ; [2112,4224) IX (argmax as float)
//   [0,6336)  SB 3-quantity rounds (after MX/IX consumed, extra barrier)
//   [6400,6416) fx ; [6416,6432) fy
#define TSTR 33
#define REFO 7128
#define MXo  0
#define IXo  2112
#define SBo  0
#define FX_  6400
#define FY_  6416
#define LDSZ 9240

static __device__ __forceinline__ f16x8 cat4(f16x2 a, f16x2 b, f16x2 c, f16x2 d) {
    f16x4 ab = __builtin_shufflevector(a, b, 0, 1, 2, 3);
    f16x4 cd = __builtin_shufflevector(c, d, 0, 1, 2, 3);
    return __builtin_shufflevector(ab, cd, 0, 1, 2, 3, 4, 5, 6, 7);
}

// exact hi/lo fp16 split of a packed f32 pair
static __device__ __forceinline__ void split2(f32x2 p, f16x2& hi, f16x2& lo) {
    hi = __builtin_bit_cast(f16x2, __builtin_amdgcn_cvt_pkrtz(p.x, p.y));
    f32x2 hf; hf.x = (float)hi.x; hf.y = (float)hi.y;
    f32x2 l = p - hf;
    lo = __builtin_bit_cast(f16x2, __builtin_amdgcn_cvt_pkrtz(l.x, l.y));
}

// Fused cost-volume + flow_reg + warp v9: conflict-free LDS (TSTR 33) +
// 3 blocks/CU x 8 high-VGPR waves (24 waves/CU WITHOUT register starvation —
// r12 showed 24 waves/CU at 52 VGPR is a wash; this keeps ~80 VGPR/wave).
// Single tar buffer (37 KB LDS) -> 3 blocks/CU at launch_bounds(512,3)
// (empirical: 2nd arg acts as min-blocks/CU on this toolchain).
// MFMA 16x16x32_f16: A = W[16f][32c], B = X[32c][16px]; D row f=grp*4+r, col=ml
// (fragment mapping verified r2..r12).
__global__ __launch_bounds__(512, 3)
void fused_kernel(const float* __restrict__ ref,
                  const float* __restrict__ tar,
                  const float* __restrict__ pw,
                  float* __restrict__ out0,
                  float* __restrict__ warped) {
    const int t    = threadIdx.x;
    const int lane = t & 63;
    const int wid  = t >> 6;            // wave = uv-chunk, 0..7
    const int ml   = lane & 15;         // B col = pixel ; A row = f
    const int grp  = lane >> 4;         // k-group (c = grp*8+j) ; D: f = grp*4+r

    // XCD-chunked bijective decode: grid 512 = 8 XCD x 64 contiguous (b,y,xq)
    const int n0 = blockIdx.x;
    const int L  = (n0 & 7) * 64 + (n0 >> 3);
    const int b  = L >> 8;
    const int y  = (L >> 2) & 63;
    const int x0 = (L & 3) * 16;

    // chunk [start, start+n), n = wid?10:11, ascending
    const int start = __builtin_amdgcn_readfirstlane(wid ? (1 + wid * 10) : 0);

    __shared__ float lds[LDSZ];

    const float* refB = ref + ((size_t)b * C_) * HW_ + y * W_ + x0;
    const float* tarB = tar + ((size_t)b * C_) * HW_;

    // per-uv decode (start is SGPR -> scalar)
    int off[11], uA[11], vA[11];
    #pragma unroll
    for (int i = 0; i < 11; ++i) {
        int uv = start + i;
        int uu = uv / 9;
        uA[i] = uu; vA[i] = uv - uu * 9;
        off[i] = (vA[i] * 24 + uu) * TSTR;
    }
    const int mlg = ml * TSTR + grp * 8;

    // ---- staging role: t<432 -> seg = t>>1 (r=seg/24,col=seg%24), 16 c each
    const int seg   = t >> 1;
    const int chalf = (t & 1) * 16;
    const bool sact = (seg < 216);
    const int sr   = seg / 24;
    const int scol = seg - sr * 24;
    const int ysr  = y + sr - 4;
    const int xg   = x0 - 4 + scol;
    const bool sok = sact && ((unsigned)ysr < 64u) && ((unsigned)xg < 64u);
    const int ysc  = ysr < 0 ? 0 : (ysr > 63 ? 63 : ysr);
    const int xgc  = xg  < 0 ? 0 : (xg  > 63 ? 63 : xg);
    const float* tS = tarB + (size_t)chalf * HW_ + ysc * W_ + xgc;

    auto STAGE = [&](int kcv, bool zfill) {
        if (sok) {
            float* dst = lds + seg * TSTR + chalf;
            const float* g = tS + (size_t)(kcv * 32) * HW_;
            #pragma unroll
            for (int c0 = 0; c0 < 16; ++c0) dst[c0] = g[(size_t)c0 * HW_];
        } else if (sact && zfill) {
            float* dst = lds + seg * TSTR + chalf;
            #pragma unroll
            for (int c0 = 0; c0 < 16; ++c0) dst[c0] = 0.f;
        }
    };

    f32x4 acc[11];
    #pragma unroll
    for (int i = 0; i < 11; ++i) acc[i] = f32x4{0.f, 0.f, 0.f, 0.f};

    // ---- prologue: stage ref (x64) + kc0 ----
    #pragma unroll
    for (int it = 0; it < 4; ++it) {
        int idx = it * 512 + t;
        int c = idx >> 4, px = idx & 15;
        lds[REFO + px * 132 + c] = refB[(size_t)c * HW_ + px] * XSCALE;
    }
    STAGE(0, true);
    __syncthreads();

    #pragma unroll
    for (int kc = 0; kc < 4; ++kc) {
        f32x4 wa = *(const f32x4*)(pw + ml * C_ + kc * 32 + grp * 8);
        f32x4 wb = *(const f32x4*)(pw + ml * C_ + kc * 32 + grp * 8 + 4);
        f16x2 wh[4], wl[4];
        {
            f32x2 p;
            p.x = wa.x * WSCALE; p.y = wa.y * WSCALE; split2(p, wh[0], wl[0]);
            p.x = wa.z * WSCALE; p.y = wa.w * WSCALE; split2(p, wh[1], wl[1]);
            p.x = wb.x * WSCALE; p.y = wb.y * WSCALE; split2(p, wh[2], wl[2]);
            p.x = wb.z * WSCALE; p.y = wb.w * WSCALE; split2(p, wh[3], wl[3]);
        }
        f16x8 whi = cat4(wh[0], wh[1], wh[2], wh[3]);
        f16x8 wlo = cat4(wl[0], wl[1], wl[2], wl[3]);

        // ref fragment: 2 x ds_read_b128, stride 132
        f32x4 rva = *(const f32x4*)(lds + REFO + ml * 132 + kc * 32 + grp * 8);
        f32x4 rvb = *(const f32x4*)(lds + REFO + ml * 132 + kc * 32 + grp * 8 + 4);
        f32x2 rv2[4];
        rv2[0].x = rva.x; rv2[0].y = rva.y;
        rv2[1].x = rva.z; rv2[1].y = rva.w;
        rv2[2].x = rvb.x; rv2[2].y = rvb.y;
        rv2[3].x = rvb.z; rv2[3].y = rvb.w;

        // uv reads: 4 x ds_read2_b32 (4B-aligned odd stride), 2 lanes/bank
#define UVBODY(i) {                                                           \
        const float* tp = lds + off[i] + mlg;                                 \
        f16x2 xh4[4], xl4[4];                                                 \
        _Pragma("unroll")                                                     \
        for (int jp = 0; jp < 4; ++jp) {                                      \
            f32x2 tj; tj.x = tp[2 * jp]; tj.y = tp[2 * jp + 1];               \
            f32x2 p  = rv2[jp] * tj;                                          \
            f32x2 p1 = p * 0.1f;                                              \
            p = __builtin_elementwise_max(p, p1);                             \
            split2(p, xh4[jp], xl4[jp]);                                      \
        }                                                                     \
        f16x8 xhi = cat4(xh4[0], xh4[1], xh4[2], xh4[3]);                     \
        f16x8 xlo = cat4(xl4[0], xl4[1], xl4[2], xl4[3]);                     \
        acc[i] = __builtin_amdgcn_mfma_f32_16x16x32_f16(whi, xhi, acc[i], 0, 0, 0); \
        acc[i] = __builtin_amdgcn_mfma_f32_16x16x32_f16(wlo, xhi, acc[i], 0, 0, 0); \
        acc[i] = __builtin_amdgcn_mfma_f32_16x16x32_f16(whi, xlo, acc[i], 0, 0, 0); }

        #pragma unroll
        for (int i = 0; i < 10; ++i) UVBODY(i);
        if (wid == 0) UVBODY(10);

        __syncthreads();                 // readers done
        if (kc < 3) {
            STAGE(kc + 1, false);        // rewrite in-bounds slots only
            __syncthreads();             // writers done
        }
    }

    // ================= register-resident flow_reg epilogue =================
    #pragma unroll
    for (int i = 0; i < 11; ++i) acc[i] = acc[i] * UNSCALE;   // exact pow2

    // ---- Phase A: per-chunk cell max/argmax in registers (ascending, >) ----
    f32x4 mx = acc[0];
    f32x4 bix = f32x4{(float)start, (float)start, (float)start, (float)start};
    #pragma unroll
    for (int i = 1; i < 10; ++i)
        #pragma unroll
        for (int r = 0; r < 4; ++r)
            if (acc[i][r] > mx[r]) { mx[r] = acc[i][r]; bix[r] = (float)(start + i); }
    if (wid == 0) {
        #pragma unroll
        for (int r = 0; r < 4; ++r)
            if (acc[10][r] > mx[r]) { mx[r] = acc[10][r]; bix[r] = 10.f; }
    }
    *(f32x4*)(lds + MXo + (wid * 4 + grp) * 66 + ml * 4) = mx;
    *(f32x4*)(lds + IXo + (wid * 4 + grp) * 66 + ml * 4) = bix;
    __syncthreads();

    // ---- Phase B: global max/argmax per cell (8 chunks ascending) ----
    f32x4 gm = *(const f32x4*)(lds + MXo + grp * 66 + ml * 4);
    f32x4 gb = *(const f32x4*)(lds + IXo + grp * 66 + ml * 4);
    #pragma unroll
    for (int ch = 1; ch < 8; ++ch) {
        f32x4 cm = *(const f32x4*)(lds + MXo + (ch * 4 + grp) * 66 + ml * 4);
        f32x4 cb = *(const f32x4*)(lds + IXo + (ch * 4 + grp) * 66 + ml * 4);
        #pragma unroll
        for (int r = 0; r < 4; ++r)
            if (cm[r] > gm[r]) { gm[r] = cm[r]; gb[r] = cb[r]; }
    }
    int ub[4], vb[4];
    #pragma unroll
    for (int r = 0; r < 4; ++r) {
        int bI = (int)gb[r];
        ub[r] = bI / 9; vb[r] = bI - 9 * ub[r];
    }

    float S[4]  = {0.f,0.f,0.f,0.f}, Aa[4] = {0.f,0.f,0.f,0.f};
    float Sx[4] = {0.f,0.f,0.f,0.f}, Sy[4] = {0.f,0.f,0.f,0.f};
    float gS[4] = {0.f,0.f,0.f,0.f}, gA[4] = {0.f,0.f,0.f,0.f};
#define PHB(i) {                                                              \
        _Pragma("unroll")                                                     \
        for (int r = 0; r < 4; ++r) {                                         \
            float d = acc[i][r] - gm[r];                                      \
            float z = __expf(d);                                              \
            gS[r] += z; gA[r] = fmaf(z, d, gA[r]);                            \
            int duc = uA[i] - ub[r], dvc = vA[i] - vb[r];                     \
            bool msk = (duc <= 3) && (duc >= -3) && (dvc <= 3) && (dvc >= -3);\
            float zm = msk ? z : 0.f, dm = msk ? d : 0.f;                     \
            S[r] += zm; Aa[r] = fmaf(zm, dm, Aa[r]);                          \
            Sx[r] = fmaf(zm, (float)(uA[i] - MD_), Sx[r]);                    \
            Sy[r] = fmaf(zm, (float)(vA[i] - MD_), Sy[r]);                    \
        } }
    #pragma unroll
    for (int i = 0; i < 10; ++i) PHB(i);
    if (wid == 0) PHB(10);
    __syncthreads();                     // MX/IX consumed -> SB may overlay

    // ---- Phase C: 2 rounds of 3 partial sums (SB overlays dead MX/IX) ----
    const int cml = t & 15, cgrp = (t >> 4) & 3;   // t<64 reduction cell
#define ROUND3(QA, QB, QC, RA, RB, RC) {                                      \
        *(f32x4*)(lds + SBo + ((0 * 8 + wid) * 4 + grp) * 66 + ml * 4) =      \
            f32x4{QA[0], QA[1], QA[2], QA[3]};                                \
        *(f32x4*)(lds + SBo + ((1 * 8 + wid) * 4 + grp) * 66 + ml * 4) =      \
            f32x4{QB[0], QB[1], QB[2], QB[3]};                                \
        *(f32x4*)(lds + SBo + ((2 * 8 + wid) * 4 + grp) * 66 + ml * 4) =      \
            f32x4{QC[0], QC[1], QC[2], QC[3]};                                \
        __syncthreads();                                                      \
        if (t < 64) {                                                         \
            f32x4 sa = *(const f32x4*)(lds + SBo + ((0 * 8) * 4 + cgrp) * 66 + cml * 4); \
            f32x4 sb = *(const f32x4*)(lds + SBo + ((1 * 8) * 4 + cgrp) * 66 + cml * 4); \
            f32x4 sc = *(const f32x4*)(lds + SBo + ((2 * 8) * 4 + cgrp) * 66 + cml * 4); \
            _Pragma("unroll")                                                 \
            for (int ch = 1; ch < 8; ++ch) {                                  \
                sa += *(const f32x4*)(lds + SBo + ((0 * 8 + ch) * 4 + cgrp) * 66 + cml * 4); \
                sb += *(const f32x4*)(lds + SBo + ((1 * 8 + ch) * 4 + cgrp) * 66 + cml * 4); \
                sc += *(const f32x4*)(lds + SBo + ((2 * 8 + ch) * 4 + cgrp) * 66 + cml * 4); \
            }                                                                 \
            RA = sa; RB = sb; RC = sc;                                        \
        }                                                                     \
        __syncthreads(); }
    f32x4 r0v, r1v, r2v, r3v, r4v, r5v;
    ROUND3(S,  Aa, Sx, r0v, r1v, r2v)
    ROUND3(Sy, gS, gA, r3v, r4v, r5v)

    if (t < 64) {
        #pragma unroll
        for (int r = 0; r < 4; ++r) {
            float invS = 1.f / r0v[r];
            float outx = r2v[r] * invS;
            float outy = r3v[r] * invS;
            float lent = (logf(r0v[r]) - r1v[r] * invS) * (1.0f / logf(49.0f));
            float gent = (logf(r4v[r]) - r5v[r] / r4v[r]) * (1.0f / logf(81.0f));
            float* op = out0 + ((size_t)(b * F_ + cgrp * 4 + r) * 4) * HW_
                      + y * W_ + x0 + cml;
            op[0 * HW_] = outx;
            op[1 * HW_] = outy;
            op[2 * HW_] = lent;
            op[3 * HW_] = gent;
            if (r == 0 && cgrp == 0) { lds[FX_ + cml] = outx; lds[FY_ + cml] = outy; }
        }
    }
    __syncthreads();

    // ---- fused warp tail: 16 px x 128 c (flow = f0) ----
    {
        const int pxi = t & 15;
        const int xw  = x0 + pxi;
        float fx = lds[FX_ + pxi], fy = lds[FY_ + pxi];
        float pxw = (float)xw + fx;
        float pyw = (float)y  + fy;
        bool inb = (fabsf(2.0f * pxw / 63.0f - 1.0f) < 1.0f) &&
                   (fabsf(2.0f * pyw / 63.0f - 1.0f) < 1.0f);
        float xf = floorf(pxw), yf = floorf(pyw);
        float wx = pxw - xf, wy = pyw - yf;
        int x0i = (int)xf, y0i = (int)yf;
        auto offn = [&](int yi, int xi, float wgt, float& mw) -> int {
            bool v = ((unsigned)xi < (unsigned)W_) && ((unsigned)yi < (unsigned)H_);
            int xc = xi < 0 ? 0 : (xi > W_ - 1 ? W_ - 1 : xi);
            int yc = yi < 0 ? 0 : (yi > H_ - 1 ? H_ - 1 : yi);
            mw = v ? wgt : 0.f;
            return yc * W_ + xc;
        };
        float m00, m01, m10, m11;
        int o00 = offn(y0i,     x0i,     (1.f - wx) * (1.f - wy), m00);
        int o01 = offn(y0i,     x0i + 1, wx * (1.f - wy),         m01);
        int o10 = offn(y0i + 1, x0i,     (1.f - wx) * wy,         m10);
        int o11 = offn(y0i + 1, x0i + 1, wx * wy,                 m11);
        #pragma unroll
        for (int it = 0; it < 4; ++it) {
            int c = (t >> 4) + 32 * it;
            const float* img = tarB + (size_t)c * HW_;
            float a = img[o00] * m00 + img[o01] * m01
                    + img[o10] * m10 + img[o11] * m11;
            warped[((size_t)(b * C_ + c)) * HW_ + y * W_ + xw] = inb ? a : 0.f;
        }
    }
}

extern "C" void kernel_launch(void* const* d_in, const int* in_sizes, int n_in,
                              void* d_out, int out_size, void* d_ws, size_t ws_size,
                              hipStream_t stream) {
    const float* ref = (const float*)d_in[0];
    const float* tar = (const float*)d_in[1];
    const float* pw  = (const float*)d_in[2];
    float* out0 = (float*)d_out;                       // (B*F, 4, H, W)
    float* out1 = out0 + (size_t)BF_ * 4 * HW_;        // (B, C, H, W)
    (void)d_ws; (void)ws_size;                         // workspace unused

    fused_kernel<<<512, 512, 0, stream>>>(ref, tar, pw, out0, out1);
}